// Round 1
// baseline (209.026 us; speedup 1.0000x reference)
//
#include <hip/hip_runtime.h>

// Fold / col2im: x[16, 9, 512, 512] f32 -> out[16, 1, 512, 512] f32
// out[b,p,q] = sum_{i,j in 0..2} x[b, i*3+j, p+1-i, q+1-j]  (OOB taps = 0)
//
// Memory-bound: 151 MB read + 17 MB write, no reuse. One thread per 4
// consecutive output columns; 9 shifted 16B loads + 1 aligned 16B store.

constexpr int B = 16;
constexpr int C = 9;
constexpr int H = 512;
constexpr int W = 512;
constexpr int WV = W / 4;  // float4 groups per row

// 4-byte-aligned float4: tap loads are shifted by +/-1 element (4 B), so we
// must not promise 16B alignment to the compiler.
typedef float f4_u __attribute__((ext_vector_type(4), aligned(4)));

__global__ __launch_bounds__(256) void fold_kernel(const float* __restrict__ x,
                                                   float* __restrict__ out) {
    const int tid = blockIdx.x * blockDim.x + threadIdx.x;  // [0, B*H*WV)
    const int qv = tid % WV;
    const int t2 = tid / WV;
    const int p  = t2 % H;
    const int b  = t2 / H;
    const int q0 = qv * 4;

    const size_t plane = (size_t)H * W;
    const float* xb = x + (size_t)b * C * plane;

    float ax = 0.f, ay = 0.f, az = 0.f, aw = 0.f;
    const bool interior = (qv != 0) & (qv != WV - 1);

#pragma unroll
    for (int i = 0; i < 3; ++i) {
        const int r = p + 1 - i;
        if (r < 0 || r >= H) continue;  // padded row -> zero contribution
#pragma unroll
        for (int j = 0; j < 3; ++j) {
            const float* xrow = xb + (size_t)(i * 3 + j) * plane + (size_t)r * W;
            const int c0 = q0 + 1 - j;  // leftmost column of this tap's 4-vector
            if (interior) {
                f4_u v = *reinterpret_cast<const f4_u*>(xrow + c0);
                ax += v.x; ay += v.y; az += v.z; aw += v.w;
            } else {
                // qv==0 or qv==WV-1: clip columns to [0, W)
                if (c0 >= 0 && c0 < W)         ax += xrow[c0];
                if (c0 + 1 >= 0 && c0 + 1 < W) ay += xrow[c0 + 1];
                if (c0 + 2 >= 0 && c0 + 2 < W) az += xrow[c0 + 2];
                if (c0 + 3 >= 0 && c0 + 3 < W) aw += xrow[c0 + 3];
            }
        }
    }

    // out offset = ((b*H + p)*W + q0) = tid*4, 16B aligned.
    f4_u r;
    r.x = ax; r.y = ay; r.z = az; r.w = aw;
    *reinterpret_cast<f4_u*>(out + (size_t)tid * 4) = r;
}

extern "C" void kernel_launch(void* const* d_in, const int* in_sizes, int n_in,
                              void* d_out, int out_size, void* d_ws, size_t ws_size,
                              hipStream_t stream) {
    const float* x = (const float*)d_in[0];
    float* out = (float*)d_out;
    const int n_threads = B * H * WV;          // 16*512*128 = 1,048,576
    const int block = 256;
    const int grid = n_threads / block;        // 4096
    fold_kernel<<<grid, block, 0, stream>>>(x, out);
}